// Round 12
// baseline (109.199 us; speedup 1.0000x reference)
//
#include <hip/hip_runtime.h>

typedef float f4 __attribute__((ext_vector_type(4)));

#define N_SEL   8192
#define N_FEAT  256
#define K_SUB   256
#define N_PERS  4
#define E_FULL  262144
#define E_RAW   262144
#define N_TOTAL 8192
#define EPSILON 0.5f
#define LAMB1   0.5f

// Workspace layout (7.25 MB):
#define WS_SCORE_OFF (128 * 1024)                     // score[K_SUB] f32
#define WS_CNT_OFF   (132 * 1024)                     // cnt i32, ovf_cnt i32
#define WS_CF_OFF    (256 * 1024)                     // cellfill u32[8192*32] (1 MB)
#define WS_CELLS_OFF (WS_CF_OFF + 1024 * 1024)        // cells u32[8192*32] (4xu8 ea, 1 MB)
#define WS_XQ_OFF    (WS_CELLS_OFF + 1024 * 1024)     // xq[N_SEL][256] fp8 (2 MB)
#define WS_LIST_OFF  (WS_XQ_OFF + 2 * 1024 * 1024)    // list[E_FULL] int2 (2 MB)
#define WS_OVF_OFF   (WS_LIST_OFF + 2 * 1024 * 1024)  // ovf int2[131072] (1 MB)

// ---- K1: one wave per node: 4 inverse norms + fp8 convert; score; zero
//          cellfill + cells + counters (cells MUST be zeroed every call:
//          scatter only ORs bits in, and pos assignment is replay-variant) ----
__global__ __launch_bounds__(256) void prep_kernel(const f4* __restrict__ x4,
                                                   const f4* __restrict__ w4,
                                                   f4* __restrict__ invn4,
                                                   unsigned int* __restrict__ xq,
                                                   const float* __restrict__ s,
                                                   const int* __restrict__ belong,
                                                   float* __restrict__ score,
                                                   int* __restrict__ cnts,
                                                   unsigned int* __restrict__ cellfill,
                                                   unsigned int* __restrict__ cells) {
    __shared__ float sv[K_SUB];
    __shared__ int bv[K_SUB];
    int gid = blockIdx.x * 256 + threadIdx.x;
    int n = gid >> 6;                    // node id
    int lane = threadIdx.x & 63;

    f4 xv = x4[(size_t)n * 64 + lane];

    int pk = 0;
    pk = __builtin_amdgcn_cvt_pk_fp8_f32(xv.x, xv.y, pk, false);
    pk = __builtin_amdgcn_cvt_pk_fp8_f32(xv.z, xv.w, pk, true);
    xq[(size_t)n * 64 + lane] = (unsigned int)pk;

    f4 ssv;
    #pragma unroll
    for (int p = 0; p < 4; ++p) {
        f4 h = xv * w4[p * 64 + lane];
        float ss = h.x * h.x + h.y * h.y + h.z * h.z + h.w * h.w;
        #pragma unroll
        for (int off = 32; off; off >>= 1) ss += __shfl_xor(ss, off);
        ssv[p] = ss;
    }
    if (lane == 0) {
        f4 r;
        r.x = 1.0f / (sqrtf(ssv.x) + 1e-12f);
        r.y = 1.0f / (sqrtf(ssv.y) + 1e-12f);
        r.z = 1.0f / (sqrtf(ssv.z) + 1e-12f);
        r.w = 1.0f / (sqrtf(ssv.w) + 1e-12f);
        invn4[n] = r;
    }

    if (gid < N_TOTAL * 32) {            // 262144 cells < 524288 threads
        cellfill[gid] = 0;
        cells[gid] = 0;
    }
    if (gid < 2) cnts[gid] = 0;

    if (blockIdx.x == 0) {
        int t = threadIdx.x;
        sv[t] = s[t];
        bv[t] = belong[t];
        __syncthreads();
        int myb = bv[t];
        float sum = 0.0f;
        for (int k = 0; k < K_SUB; ++k)
            if (bv[k] == myb) sum += sv[k];
        score[t] = sv[t] / sum;
    }
}

// ---- K2: raw edges -> (row,segment) cells, cap 4 (u8 col-in-seg); overflow
//          to side list (applied in finalize, after the zeros) ----
__global__ __launch_bounds__(256) void scatter_kernel(const int* __restrict__ re,
                                                      unsigned int* __restrict__ cellfill,
                                                      unsigned int* __restrict__ cells,
                                                      int2* __restrict__ ovf,
                                                      int* __restrict__ cnts) {
    int t = blockIdx.x * 256 + threadIdx.x;
    if (t >= E_RAW) return;
    int u = re[t];
    int v = re[E_RAW + t];
    int cell = u * 32 + (v >> 8);
    unsigned pos = atomicAdd(&cellfill[cell], 1u);
    if (pos < 4) {
        atomicOr(&cells[cell], ((unsigned)(v & 255)) << (8 * pos));
    } else {
        int oi = atomicAdd(&cnts[1], 1);
        int2 e; e.x = u; e.y = v;
        ovf[oi] = e;
    }
}

// ---- K3: per wave: stream one output row as 32x 1KB stores with the row's
// raw-edge contributions FOLDED INTO the stored values (no ordering waits,
// no atomics); 32 cosine edges interleaved 1:1. No barrier, no vmcnt drain.
__global__ __launch_bounds__(256) void zero_edge_kernel(f4* __restrict__ out4,
                                                        const unsigned int* __restrict__ xq,
                                                        const f4* __restrict__ w4,
                                                        const int* __restrict__ fe,
                                                        const int* __restrict__ sel_batch,
                                                        const f4* __restrict__ invn4,
                                                        const float* __restrict__ score,
                                                        const unsigned int* __restrict__ cellfill,
                                                        const unsigned int* __restrict__ cells,
                                                        int2* __restrict__ list,
                                                        int* __restrict__ cnts) {
    int b = blockIdx.x;                  // block owns rows [4b, 4b+4)
    int t = threadIdx.x;
    int lane = t & 63;
    int w = t >> 6;

    // wave's 32 edges: lanes 0-31 hold i's, lanes 32-63 hold j's
    int ebase = b * 128 + w * 32;
    int myidx = (lane < 32) ? fe[ebase + lane] : fe[E_FULL + ebase + (lane - 32)];

    // per-lane squared weights for dims [4*lane, 4*lane+4), 4 perspectives
    f4 q0 = w4[0 * 64 + lane]; q0 *= q0;
    f4 q1 = w4[1 * 64 + lane]; q1 *= q1;
    f4 q2 = w4[2 * 64 + lane]; q2 *= q2;
    f4 q3 = w4[3 * 64 + lane]; q3 *= q3;

    int rowid = b * 4 + w;
    size_t obase = (size_t)rowid * 2048;  // row base in f4 units

    // prefetch this row's 32 segment cells into lanes 0-31
    unsigned ccnt = 0, cpack = 0;
    if (lane < 32) {
        ccnt  = cellfill[rowid * 32 + lane];
        cpack = cells[rowid * 32 + lane];
    }

    // prefetch edge 0
    int ci = __shfl(myidx, 0);
    int cj = __shfl(myidx, 32);
    unsigned int xi = xq[(size_t)ci * 64 + lane];
    unsigned int xj = xq[(size_t)cj * 64 + lane];
    f4 ii = invn4[ci];
    f4 ij = invn4[cj];

    #pragma unroll 4
    for (int s = 0; s < 32; ++s) {
        // build the stored segment: zeros + this segment's raw-edge adds
        unsigned cs = __shfl(ccnt, s);
        unsigned cp = __shfl(cpack, s);
        f4 zz = (f4)0.0f;
        if (cs) {                         // wave-uniform branch (s-broadcast)
            #pragma unroll
            for (int e = 0; e < 4; ++e) {
                if ((unsigned)e < cs) {
                    unsigned c8 = (cp >> (8 * e)) & 255u;
                    if ((int)(c8 >> 2) == lane) zz[c8 & 3] += (1.0f - LAMB1);
                }
            }
        }
        out4[obase + s * 64 + lane] = zz;

        // rotate current edge into locals; prefetch next
        int i = ci, j = cj;
        unsigned int ax = xi, bx = xj;
        f4 aii = ii, aij = ij;
        if (s < 31) {
            ci = __shfl(myidx, s + 1);
            cj = __shfl(myidx, 32 + s + 1);
            xi = xq[(size_t)ci * 64 + lane];
            xj = xq[(size_t)cj * 64 + lane];
            ii = invn4[ci];
            ij = invn4[cj];
        }

        // decode fp8 dims (literal selectors required by the builtin)
        float pd0 = __builtin_amdgcn_cvt_f32_fp8((int)ax, 0) *
                    __builtin_amdgcn_cvt_f32_fp8((int)bx, 0);
        float pd1 = __builtin_amdgcn_cvt_f32_fp8((int)ax, 1) *
                    __builtin_amdgcn_cvt_f32_fp8((int)bx, 1);
        float pd2 = __builtin_amdgcn_cvt_f32_fp8((int)ax, 2) *
                    __builtin_amdgcn_cvt_f32_fp8((int)bx, 2);
        float pd3 = __builtin_amdgcn_cvt_f32_fp8((int)ax, 3) *
                    __builtin_amdgcn_cvt_f32_fp8((int)bx, 3);

        float a0 = fmaf(pd3, q0.w, fmaf(pd2, q0.z, fmaf(pd1, q0.y, pd0 * q0.x)));
        float a1 = fmaf(pd3, q1.w, fmaf(pd2, q1.z, fmaf(pd1, q1.y, pd0 * q1.x)));
        float a2 = fmaf(pd3, q2.w, fmaf(pd2, q2.z, fmaf(pd1, q2.y, pd0 * q2.x)));
        float a3 = fmaf(pd3, q3.w, fmaf(pd2, q3.z, fmaf(pd1, q3.y, pd0 * q3.x)));

        float v = a0 * (aii.x * aij.x) + a1 * (aii.y * aij.y) +
                  a2 * (aii.z * aij.z) + a3 * (aii.w * aij.w);
        v += __shfl_xor(v, 1);
        v += __shfl_xor(v, 2);
        v += __shfl_xor(v, 4);
        v += __shfl_xor(v, 8);
        v += __shfl_xor(v, 16);
        v += __shfl_xor(v, 32);

        if (lane == 0 && i != j) {
            v *= 0.25f;
            if (v > EPSILON) {
                float val = v * score[sel_batch[i]] * LAMB1;
                int idx = atomicAdd(&cnts[0], 1);
                int2 ent;
                ent.x = (i << 13) | j;
                ent.y = __float_as_int(val);
                list[idx] = ent;
            }
        }
    }
}

// ---- K4: overflow raw edges (accumulate) + dedup'd learned-edge scatter ----
__global__ __launch_bounds__(256) void finalize_kernel(const int2* __restrict__ list,
                                                       const int2* __restrict__ ovf,
                                                       const int* __restrict__ cnts,
                                                       const int* __restrict__ sel_map,
                                                       float* __restrict__ out) {
    int t = blockIdx.x * 256 + threadIdx.x;
    int m = cnts[1];
    if (t < m) {
        int2 e = ovf[t];
        atomicAdd(&out[(size_t)e.x * N_TOTAL + e.y], 1.0f - LAMB1);
    }
    int n = cnts[0];
    if (t < n) {
        int2 ek = list[t];
        bool first = true;
        for (int l = 0; l < t; ++l)
            if (list[l].x == ek.x) { first = false; break; }
        if (first) {
            int i = ek.x >> 13;
            int j = ek.x & (N_SEL - 1);
            atomicAdd(&out[(size_t)sel_map[i] * N_TOTAL + sel_map[j]],
                      __int_as_float(ek.y));
        }
    }
}

extern "C" void kernel_launch(void* const* d_in, const int* in_sizes, int n_in,
                              void* d_out, int out_size, void* d_ws, size_t ws_size,
                              hipStream_t stream) {
    const float* x         = (const float*)d_in[0];
    const float* mw        = (const float*)d_in[1];
    const int* sel_batch   = (const int*)d_in[2];
    const int* sel_map     = (const int*)d_in[3];
    const int* sel_belong  = (const int*)d_in[4];
    const float* sel_score = (const float*)d_in[5];
    const int* fe          = (const int*)d_in[6];
    const int* re          = (const int*)d_in[7];
    float* out             = (float*)d_out;

    char* ws           = (char*)d_ws;
    f4* invn4          = (f4*)ws;
    float* score       = (float*)(ws + WS_SCORE_OFF);
    int* cnts          = (int*)(ws + WS_CNT_OFF);
    unsigned int* cf   = (unsigned int*)(ws + WS_CF_OFF);
    unsigned int* cel  = (unsigned int*)(ws + WS_CELLS_OFF);
    unsigned int* xq   = (unsigned int*)(ws + WS_XQ_OFF);
    int2* list         = (int2*)(ws + WS_LIST_OFF);
    int2* ovf          = (int2*)(ws + WS_OVF_OFF);

    prep_kernel<<<2048, 256, 0, stream>>>(
        (const f4*)x, (const f4*)mw, invn4, xq, sel_score, sel_belong, score,
        cnts, cf, cel);
    scatter_kernel<<<E_RAW / 256, 256, 0, stream>>>(re, cf, cel, ovf, cnts);
    zero_edge_kernel<<<2048, 256, 0, stream>>>(
        (f4*)out, xq, (const f4*)mw, fe, sel_batch,
        invn4, score, cf, cel, list, cnts);
    finalize_kernel<<<1024, 256, 0, stream>>>(list, ovf, cnts, sel_map, out);
}

// Round 13
// 92.063 us; speedup vs baseline: 1.1861x; 1.1861x over previous
//
#include <hip/hip_runtime.h>

typedef float f4 __attribute__((ext_vector_type(4)));

#define N_SEL   8192
#define N_FEAT  256
#define K_SUB   256
#define N_PERS  4
#define E_FULL  262144
#define E_RAW   262144
#define N_TOTAL 8192
#define EPSILON 0.5f
#define LAMB1   0.5f

// Workspace layout:
#define WS_SCORE_OFF  (128 * 1024)                    // score[K_SUB] f32
#define WS_CNT_OFF    (132 * 1024)                    // pass counter i32
#define WS_XQ_OFF     (256 * 1024)                    // xq[N_SEL][256] fp8 (2 MB)
#define WS_LIST_OFF   (WS_XQ_OFF + 2 * 1024 * 1024)   // list[E_FULL] int2 (2 MB)

// ---- K1: one wave per node: 4 inverse norms + fp8 convert + score + cnt=0 ----
__global__ __launch_bounds__(256) void prep_kernel(const f4* __restrict__ x4,
                                                   const f4* __restrict__ w4,
                                                   f4* __restrict__ invn4,
                                                   unsigned int* __restrict__ xq,
                                                   const float* __restrict__ s,
                                                   const int* __restrict__ belong,
                                                   float* __restrict__ score,
                                                   int* __restrict__ cnt) {
    __shared__ float sv[K_SUB];
    __shared__ int bv[K_SUB];
    int gid = blockIdx.x * 256 + threadIdx.x;
    int n = gid >> 6;                    // node id
    int lane = threadIdx.x & 63;

    f4 xv = x4[(size_t)n * 64 + lane];

    int pk = 0;
    pk = __builtin_amdgcn_cvt_pk_fp8_f32(xv.x, xv.y, pk, false);
    pk = __builtin_amdgcn_cvt_pk_fp8_f32(xv.z, xv.w, pk, true);
    xq[(size_t)n * 64 + lane] = (unsigned int)pk;

    f4 ssv;
    #pragma unroll
    for (int p = 0; p < 4; ++p) {
        f4 h = xv * w4[p * 64 + lane];
        float ss = h.x * h.x + h.y * h.y + h.z * h.z + h.w * h.w;
        #pragma unroll
        for (int off = 32; off; off >>= 1) ss += __shfl_xor(ss, off);
        ssv[p] = ss;
    }
    if (lane == 0) {
        f4 r;
        r.x = 1.0f / (sqrtf(ssv.x) + 1e-12f);
        r.y = 1.0f / (sqrtf(ssv.y) + 1e-12f);
        r.z = 1.0f / (sqrtf(ssv.z) + 1e-12f);
        r.w = 1.0f / (sqrtf(ssv.w) + 1e-12f);
        invn4[n] = r;
    }

    if (gid == 0) *cnt = 0;

    if (blockIdx.x == 0) {
        int t = threadIdx.x;
        sv[t] = s[t];
        bv[t] = belong[t];
        __syncthreads();
        int myb = bv[t];
        float sum = 0.0f;
        for (int k = 0; k < K_SUB; ++k)
            if (bv[k] == myb) sum += sv[k];
        score[t] = sv[t] / sum;
    }
}

// ---- K2: per wave: one output row (32x 1KB zero stores) + 32 cosine edges,
// interleaved 1:1. CRITICAL ORDER per iteration: prefetch gathers FIRST, then
// the store, then compute. vmcnt retires in issue order, so if the store were
// issued before the gathers, every compute would stall on the previous
// store's drain to L2 (HBM write backpressure). Gathers-first means compute
// only ever waits on L2-hit gather latency. No barrier, no vmcnt(0) drain.
__global__ __launch_bounds__(256) void zero_edge_kernel(f4* __restrict__ out4,
                                                        const unsigned int* __restrict__ xq,
                                                        const f4* __restrict__ w4,
                                                        const int* __restrict__ fe,
                                                        const int* __restrict__ sel_batch,
                                                        const f4* __restrict__ invn4,
                                                        const float* __restrict__ score,
                                                        int2* __restrict__ list,
                                                        int* __restrict__ cnt) {
    int b = blockIdx.x;                  // block owns rows [4b, 4b+4)
    int t = threadIdx.x;
    int lane = t & 63;
    int w = t >> 6;

    // wave's 32 edges: lanes 0-31 hold i's, lanes 32-63 hold j's
    int ebase = b * 128 + w * 32;
    int myidx = (lane < 32) ? fe[ebase + lane] : fe[E_FULL + ebase + (lane - 32)];

    // per-lane squared weights for dims [4*lane, 4*lane+4), 4 perspectives
    f4 q0 = w4[0 * 64 + lane]; q0 *= q0;
    f4 q1 = w4[1 * 64 + lane]; q1 *= q1;
    f4 q2 = w4[2 * 64 + lane]; q2 *= q2;
    f4 q3 = w4[3 * 64 + lane]; q3 *= q3;

    int rowid = b * 4 + w;
    size_t obase = (size_t)rowid * 2048;  // row base in f4 units
    f4 z = (f4)0.0f;

    // prologue: load edge 0's operands
    int ci = __shfl(myidx, 0);
    int cj = __shfl(myidx, 32);
    unsigned int xi = xq[(size_t)ci * 64 + lane];
    unsigned int xj = xq[(size_t)cj * 64 + lane];
    f4 ii = invn4[ci];
    f4 ij = invn4[cj];

    #pragma unroll 4
    for (int s = 0; s < 32; ++s) {
        // (1) rotate current edge into locals
        int i = ci, j = cj;
        unsigned int ax = xi, bx = xj;
        f4 aii = ii, aij = ij;

        // (2) prefetch next edge's gathers — issued BEFORE this step's store
        if (s < 31) {
            ci = __shfl(myidx, s + 1);
            cj = __shfl(myidx, 32 + s + 1);
            xi = xq[(size_t)ci * 64 + lane];
            xj = xq[(size_t)cj * 64 + lane];
            ii = invn4[ci];
            ij = invn4[cj];
        }
        // pin issue order: gathers above may not sink below, store below may
        // not hoist above
        __builtin_amdgcn_sched_barrier(0);

        // (3) this step's 1KB zero store (younger than all pending gathers:
        //     its drain never gates any compute wait)
        out4[obase + s * 64 + lane] = z;

        // (4) compute edge s (waits only on its own gathers)
        float pd0 = __builtin_amdgcn_cvt_f32_fp8((int)ax, 0) *
                    __builtin_amdgcn_cvt_f32_fp8((int)bx, 0);
        float pd1 = __builtin_amdgcn_cvt_f32_fp8((int)ax, 1) *
                    __builtin_amdgcn_cvt_f32_fp8((int)bx, 1);
        float pd2 = __builtin_amdgcn_cvt_f32_fp8((int)ax, 2) *
                    __builtin_amdgcn_cvt_f32_fp8((int)bx, 2);
        float pd3 = __builtin_amdgcn_cvt_f32_fp8((int)ax, 3) *
                    __builtin_amdgcn_cvt_f32_fp8((int)bx, 3);

        float a0 = fmaf(pd3, q0.w, fmaf(pd2, q0.z, fmaf(pd1, q0.y, pd0 * q0.x)));
        float a1 = fmaf(pd3, q1.w, fmaf(pd2, q1.z, fmaf(pd1, q1.y, pd0 * q1.x)));
        float a2 = fmaf(pd3, q2.w, fmaf(pd2, q2.z, fmaf(pd1, q2.y, pd0 * q2.x)));
        float a3 = fmaf(pd3, q3.w, fmaf(pd2, q3.z, fmaf(pd1, q3.y, pd0 * q3.x)));

        float v = a0 * (aii.x * aij.x) + a1 * (aii.y * aij.y) +
                  a2 * (aii.z * aij.z) + a3 * (aii.w * aij.w);
        v += __shfl_xor(v, 1);
        v += __shfl_xor(v, 2);
        v += __shfl_xor(v, 4);
        v += __shfl_xor(v, 8);
        v += __shfl_xor(v, 16);
        v += __shfl_xor(v, 32);

        if (lane == 0 && i != j) {
            v *= 0.25f;
            if (v > EPSILON) {
                float val = v * score[sel_batch[i]] * LAMB1;
                int idx = atomicAdd(cnt, 1);
                int2 ent;
                ent.x = (i << 13) | j;
                ent.y = __float_as_int(val);
                list[idx] = ent;
            }
        }
    }
}

// ---- K3: raw-edge atomics (ordered after K2's zeros by stream dependency) +
//          dedup'd learned-edge scatter ----
__global__ __launch_bounds__(256) void raw_finalize_kernel(const int* __restrict__ re,
                                                           const int2* __restrict__ list,
                                                           const int* __restrict__ cnt,
                                                           const int* __restrict__ sel_map,
                                                           float* __restrict__ out) {
    int t = blockIdx.x * 256 + threadIdx.x;
    if (t < E_RAW) {
        int u = re[t];
        int v = re[E_RAW + t];
        atomicAdd(&out[(size_t)u * N_TOTAL + v], 1.0f - LAMB1);
    }
    int n = *cnt;
    if (t < n) {
        int2 ek = list[t];
        bool first = true;
        for (int l = 0; l < t; ++l)
            if (list[l].x == ek.x) { first = false; break; }
        if (first) {
            int i = ek.x >> 13;
            int j = ek.x & (N_SEL - 1);
            atomicAdd(&out[(size_t)sel_map[i] * N_TOTAL + sel_map[j]],
                      __int_as_float(ek.y));
        }
    }
}

extern "C" void kernel_launch(void* const* d_in, const int* in_sizes, int n_in,
                              void* d_out, int out_size, void* d_ws, size_t ws_size,
                              hipStream_t stream) {
    const float* x         = (const float*)d_in[0];
    const float* mw        = (const float*)d_in[1];
    const int* sel_batch   = (const int*)d_in[2];
    const int* sel_map     = (const int*)d_in[3];
    const int* sel_belong  = (const int*)d_in[4];
    const float* sel_score = (const float*)d_in[5];
    const int* fe          = (const int*)d_in[6];
    const int* re          = (const int*)d_in[7];
    float* out             = (float*)d_out;

    char* ws         = (char*)d_ws;
    f4* invn4        = (f4*)ws;
    float* score     = (float*)(ws + WS_SCORE_OFF);
    int* cnt         = (int*)(ws + WS_CNT_OFF);
    unsigned int* xq = (unsigned int*)(ws + WS_XQ_OFF);
    int2* list       = (int2*)(ws + WS_LIST_OFF);

    prep_kernel<<<2048, 256, 0, stream>>>(
        (const f4*)x, (const f4*)mw, invn4, xq, sel_score, sel_belong, score, cnt);
    zero_edge_kernel<<<2048, 256, 0, stream>>>(
        (f4*)out, xq, (const f4*)mw, fe, sel_batch,
        invn4, score, list, cnt);
    raw_finalize_kernel<<<1024, 256, 0, stream>>>(re, list, cnt, sel_map, out);
}